// Round 6
// baseline (280.096 us; speedup 1.0000x reference)
//
#include <hip/hip_runtime.h>

#define NN 50000
#define NE 800000
#define H  64
#define SCAN_B 196  // ceil(NN/256); 196*256 = 50176

typedef __attribute__((ext_vector_type(8))) short bf16x8;
typedef __attribute__((ext_vector_type(4))) float f32x4;

__device__ __forceinline__ unsigned short f2bf(float f) {
  unsigned int u = __builtin_bit_cast(unsigned int, f);
  u += 0x7FFFu + ((u >> 16) & 1u);  // RNE
  return (unsigned short)(u >> 16);
}
__device__ __forceinline__ float bf2f(unsigned short u) {
  unsigned int v = ((unsigned int)u) << 16;
  return __builtin_bit_cast(float, v);
}

// ---------- count in-degree (dst) ----------
__global__ __launch_bounds__(256) void k_zero(int* __restrict__ cnt) {
  int i = blockIdx.x * 256 + threadIdx.x;
  if (i < NN) cnt[i] = 0;
}

__global__ __launch_bounds__(256) void k_hist(const int* __restrict__ ei,
                                              int* __restrict__ cnt) {
  int e = blockIdx.x * 256 + threadIdx.x;
  atomicAdd(&cnt[ei[NE + e]], 1);
}

// ---------- hierarchical exclusive scan ----------
__global__ __launch_bounds__(256) void k_scan_local(const int* __restrict__ cnt,
                                                    int* __restrict__ loc,
                                                    int* __restrict__ bsum) {
  __shared__ int sh[256];
  const int t = threadIdx.x;
  const int i = blockIdx.x * 256 + t;
  const int v = (i < NN) ? cnt[i] : 0;
  sh[t] = v;
  __syncthreads();
  int val = v;
#pragma unroll
  for (int off = 1; off < 256; off <<= 1) {
    int o = (t >= off) ? sh[t - off] : 0;
    __syncthreads();
    val += o;
    sh[t] = val;
    __syncthreads();
  }
  if (i < NN) loc[i] = val - v;  // exclusive
  if (t == 255) bsum[blockIdx.x] = val;
}

__global__ __launch_bounds__(256) void k_scan_bsum(const int* __restrict__ bsum,
                                                   int* __restrict__ boff) {
  __shared__ int sh[256];
  const int t = threadIdx.x;
  const int v = (t < SCAN_B) ? bsum[t] : 0;
  sh[t] = v;
  __syncthreads();
  int val = v;
#pragma unroll
  for (int off = 1; off < 256; off <<= 1) {
    int o = (t >= off) ? sh[t - off] : 0;
    __syncthreads();
    val += o;
    sh[t] = val;
    __syncthreads();
  }
  if (t < SCAN_B) boff[t] = val - v;  // exclusive
}

__global__ __launch_bounds__(256) void k_scan_add(const int* __restrict__ loc,
                                                  const int* __restrict__ boff,
                                                  const int* __restrict__ cnt,
                                                  int* __restrict__ rowptr,
                                                  int* __restrict__ cursor,
                                                  float* __restrict__ dinv) {
  const int i = blockIdx.x * 256 + threadIdx.x;
  if (i < NN) {
    const int r = loc[i] + boff[blockIdx.x];
    rowptr[i] = r;
    cursor[i] = r;
    dinv[i] = rsqrtf((float)(cnt[i] + 1));  // +1 self-loop
  }
  if (i == 0) rowptr[NN] = NE;
}

// ---------- node encoder + h0@W_gcn; htb = bf16(ht * dinv[n]) ----------
__global__ __launch_bounds__(256) void k_node(
    const float* __restrict__ x, const float* __restrict__ W_ne,
    const float* __restrict__ b_ne, const float* __restrict__ W_gcn,
    const float* __restrict__ dinv, unsigned short* __restrict__ htb) {
  __shared__ float sh[4][H];
  const int lane = threadIdx.x & 63;
  const int wv   = threadIdx.x >> 6;
  const int n    = blockIdx.x * 4 + wv;

  float acc = b_ne[lane];
#pragma unroll
  for (int k = 0; k < 5; ++k) acc = fmaf(x[n * 5 + k], W_ne[k * H + lane], acc);
  acc = fmaxf(acc, 0.0f);
  sh[wv][lane] = acc;
  __syncthreads();

  float hv = 0.0f;
#pragma unroll 8
  for (int k = 0; k < H; ++k) hv = fmaf(sh[wv][k], W_gcn[k * H + lane], hv);

  htb[(size_t)n * H + lane] = f2bf(hv * dinv[n]);
}

// ---------- reorder: csr_src grouped by dst ----------
__global__ __launch_bounds__(256) void k_reorder(const int* __restrict__ ei,
                                                 int* __restrict__ cursor,
                                                 int* __restrict__ csr_src) {
  int e = blockIdx.x * 256 + threadIdx.x;
  int s = ei[e], d = ei[NE + e];
  int pos = atomicAdd(&cursor[d], 1);
  csr_src[pos] = s;
}

// ---------- gather: hgb[d] = bf16(dinv[d]*(htb[d] + sum htb[src]) + b_gcn) ----------
__global__ __launch_bounds__(256) void k_gather(
    const int* __restrict__ rowptr, const int* __restrict__ csr_src,
    const unsigned short* __restrict__ htb, const float* __restrict__ dinv,
    const float* __restrict__ b_gcn, unsigned short* __restrict__ hgb) {
  const int lane = threadIdx.x & 63;
  const int wv   = threadIdx.x >> 6;
  const int n    = blockIdx.x * 4 + wv;  // NN % 4 == 0
  const int beg = rowptr[n], end = rowptr[n + 1];

  float sum = bf2f(htb[(size_t)n * H + lane]);  // self-loop term
  int i = beg;
#pragma unroll 1
  for (; i + 4 <= end; i += 4) {
    const int s0 = csr_src[i], s1 = csr_src[i + 1];
    const int s2 = csr_src[i + 2], s3 = csr_src[i + 3];
    const float v0 = bf2f(htb[(size_t)s0 * H + lane]);
    const float v1 = bf2f(htb[(size_t)s1 * H + lane]);
    const float v2 = bf2f(htb[(size_t)s2 * H + lane]);
    const float v3 = bf2f(htb[(size_t)s3 * H + lane]);
    sum += (v0 + v1) + (v2 + v3);
  }
#pragma unroll 1
  for (; i < end; ++i) sum += bf2f(htb[(size_t)csr_src[i] * H + lane]);

  hgb[(size_t)n * H + lane] = f2bf(fmaf(dinv[n], sum, b_gcn[lane]));
}

// ---------- prep: W1 (f32 [192][64]) -> W1t (bf16 [64][192]) ----------
__global__ __launch_bounds__(256) void k_prep_w1t(const float* __restrict__ W1,
                                                  unsigned short* __restrict__ W1t) {
  const int t = blockIdx.x * 256 + threadIdx.x;  // 48*256 = 12288 = 64*192
  const int h = t / 192, k = t % 192;
  W1t[h * 192 + k] = f2bf(W1[k * H + h]);
}

// ---------- MFMA edge MLP: h-split across 4 waves, W1 frags in registers ----------
// block = 256 threads = 4 waves; wave wv owns h in [wv*16, wv*16+16).
// All waves process the same 8 tiles of 16 edges (128 edges/block).
__global__ __launch_bounds__(256, 3) void k_mlp_mfma(
    const int* __restrict__ ei, const float* __restrict__ eattr,
    const unsigned short* __restrict__ hgb, const unsigned short* __restrict__ W1t,
    const float* __restrict__ W_ee, const float* __restrict__ b_ee,
    const float* __restrict__ b1, const float* __restrict__ W2,
    const float* __restrict__ b2, float* __restrict__ out) {
  __shared__ float sred[8][4][16];  // [tile][wave][edge]

  const int lane = threadIdx.x & 63;
  const int wv   = threadIdx.x >> 6;
  const int l15  = lane & 15;
  const int l4   = lane >> 4;

  // persistent W1^T fragments for THIS wave's h-block: row h = wv*16+l15
  bf16x8 wf0, wf1, wf2, wf3, wf4, wf5;
  {
    const unsigned short* wp = W1t + (wv * 16 + l15) * 192 + l4 * 8;
    wf0 = *(const bf16x8*)(wp);
    wf1 = *(const bf16x8*)(wp + 32);
    wf2 = *(const bf16x8*)(wp + 64);
    wf3 = *(const bf16x8*)(wp + 96);
    wf4 = *(const bf16x8*)(wp + 128);
    wf5 = *(const bf16x8*)(wp + 160);
  }

  // D-layout rows this lane produces: h = wv*16 + l4*4 + r
  float b1v[4], w2v[4];
#pragma unroll
  for (int r = 0; r < 4; ++r) {
    b1v[r] = b1[wv * 16 + l4 * 4 + r];
    w2v[r] = W2[wv * 16 + l4 * 4 + r];
  }
  float wee[16], bee[16];
#pragma unroll
  for (int j = 0; j < 8; ++j) {
    wee[j]     = W_ee[l4 * 8 + j];      bee[j]     = b_ee[l4 * 8 + j];
    wee[8 + j] = W_ee[32 + l4 * 8 + j]; bee[8 + j] = b_ee[32 + l4 * 8 + j];
  }

  // all 128 edge indices of this block, 2 regs per array
  const int ebase = blockIdx.x * 128;
  const int   ia = ei[ebase + lane],        ib = ei[ebase + 64 + lane];
  const int   da = ei[NE + ebase + lane],   db = ei[NE + ebase + 64 + lane];
  const float eaa = eattr[ebase + lane],    eab = eattr[ebase + 64 + lane];

  // double-buffered edge fragments (B-operand): col = l15, k = l4*8+j (+32)
  bf16x8 As0, As1, Ad0, Ad1, Bs0, Bs1, Bd0, Bd1;
  {
    const int s0 = __shfl(ia, l15), d0 = __shfl(da, l15);
    As0 = *(const bf16x8*)(hgb + (size_t)s0 * H + l4 * 8);
    As1 = *(const bf16x8*)(hgb + (size_t)s0 * H + 32 + l4 * 8);
    Ad0 = *(const bf16x8*)(hgb + (size_t)d0 * H + l4 * 8);
    Ad1 = *(const bf16x8*)(hgb + (size_t)d0 * H + 32 + l4 * 8);
  }

  auto tile_body = [&](int t, bf16x8& cs0, bf16x8& cs1, bf16x8& cd0, bf16x8& cd1,
                       bf16x8& ns0, bf16x8& ns1, bf16x8& nd0, bf16x8& nd1) {
    if (t < 7) {  // prefetch next tile's gathers (overlap with MFMAs below)
      const int sl = ((t + 1) & 3) * 16 + l15;
      const int sn = __shfl((t + 1) < 4 ? ia : ib, sl);
      const int dn = __shfl((t + 1) < 4 ? da : db, sl);
      ns0 = *(const bf16x8*)(hgb + (size_t)sn * H + l4 * 8);
      ns1 = *(const bf16x8*)(hgb + (size_t)sn * H + 32 + l4 * 8);
      nd0 = *(const bf16x8*)(hgb + (size_t)dn * H + l4 * 8);
      nd1 = *(const bf16x8*)(hgb + (size_t)dn * H + 32 + l4 * 8);
    }
    const float eat = __shfl(t < 4 ? eaa : eab, (t & 3) * 16 + l15);
    bf16x8 ae0, ae1;
#pragma unroll
    for (int j = 0; j < 8; ++j) {
      ae0[j] = (short)f2bf(fmaxf(fmaf(eat, wee[j], bee[j]), 0.0f));
      ae1[j] = (short)f2bf(fmaxf(fmaf(eat, wee[8 + j], bee[8 + j]), 0.0f));
    }

    f32x4 acc;
    acc[0] = b1v[0]; acc[1] = b1v[1]; acc[2] = b1v[2]; acc[3] = b1v[3];
    acc = __builtin_amdgcn_mfma_f32_16x16x32_bf16(wf0, cs0, acc, 0, 0, 0);
    acc = __builtin_amdgcn_mfma_f32_16x16x32_bf16(wf1, cs1, acc, 0, 0, 0);
    acc = __builtin_amdgcn_mfma_f32_16x16x32_bf16(wf2, cd0, acc, 0, 0, 0);
    acc = __builtin_amdgcn_mfma_f32_16x16x32_bf16(wf3, cd1, acc, 0, 0, 0);
    acc = __builtin_amdgcn_mfma_f32_16x16x32_bf16(wf4, ae0, acc, 0, 0, 0);
    acc = __builtin_amdgcn_mfma_f32_16x16x32_bf16(wf5, ae1, acc, 0, 0, 0);

    // layer-2 partial over this wave's 16 h: lane-local 4, then cross-l4 reduce
    float p = 0.0f;
#pragma unroll
    for (int r = 0; r < 4; ++r) p = fmaf(fmaxf(acc[r], 0.0f), w2v[r], p);
    p += __shfl_xor(p, 16);
    p += __shfl_xor(p, 32);
    if (lane < 16) sred[t][wv][l15] = p;
  };

#pragma unroll
  for (int t = 0; t < 8; t += 2) {
    tile_body(t,     As0, As1, Ad0, Ad1, Bs0, Bs1, Bd0, Bd1);
    tile_body(t + 1, Bs0, Bs1, Bd0, Bd1, As0, As1, Ad0, Ad1);
  }

  __syncthreads();
  const int i = threadIdx.x;
  if (i < 128) {
    const int tt = i >> 4, e = i & 15;
    out[ebase + i] = sred[tt][0][e] + sred[tt][1][e] + sred[tt][2][e] +
                     sred[tt][3][e] + b2[0];
  }
}

extern "C" void kernel_launch(void* const* d_in, const int* in_sizes, int n_in,
                              void* d_out, int out_size, void* d_ws, size_t ws_size,
                              hipStream_t stream) {
  const float* x     = (const float*)d_in[0];
  const int*   ei    = (const int*)d_in[1];
  const float* eattr = (const float*)d_in[2];
  const float* W_ne  = (const float*)d_in[3];
  const float* b_ne  = (const float*)d_in[4];
  const float* W_ee  = (const float*)d_in[5];
  const float* b_ee  = (const float*)d_in[6];
  const float* W_gcn = (const float*)d_in[7];
  const float* b_gcn = (const float*)d_in[8];
  const float* W1    = (const float*)d_in[9];
  const float* b1    = (const float*)d_in[10];
  const float* W2    = (const float*)d_in[11];
  const float* b2    = (const float*)d_in[12];
  float* out = (float*)d_out;

  char* ws = (char*)d_ws;
  unsigned short* htb = (unsigned short*)ws;                      // NN*H bf16
  unsigned short* hgb = htb + (size_t)NN * H;                     // NN*H bf16
  int*   cnt     = (int*)(hgb + (size_t)NN * H);                  // NN
  int*   rowptr  = cnt + NN;                                      // NN+1
  int*   cursor  = rowptr + NN + 1;                               // NN
  float* dinv    = (float*)(cursor + NN);                         // NN
  int*   csr_src = (int*)(dinv + NN);                             // NE
  unsigned short* W1t = (unsigned short*)(csr_src + NE);          // 64*192
  int*   loc     = (int*)(W1t + 64 * 192);                        // NN
  int*   bsum    = loc + NN;                                      // SCAN_B
  int*   boff    = bsum + SCAN_B;                                 // SCAN_B

  k_zero<<<SCAN_B, 256, 0, stream>>>(cnt);
  k_hist<<<NE / 256, 256, 0, stream>>>(ei, cnt);
  k_scan_local<<<SCAN_B, 256, 0, stream>>>(cnt, loc, bsum);
  k_scan_bsum<<<1, 256, 0, stream>>>(bsum, boff);
  k_scan_add<<<SCAN_B, 256, 0, stream>>>(loc, boff, cnt, rowptr, cursor, dinv);
  k_prep_w1t<<<48, 256, 0, stream>>>(W1, W1t);
  k_node<<<NN / 4, 256, 0, stream>>>(x, W_ne, b_ne, W_gcn, dinv, htb);
  k_reorder<<<NE / 256, 256, 0, stream>>>(ei, cursor, csr_src);
  k_gather<<<NN / 4, 256, 0, stream>>>(rowptr, csr_src, htb, dinv, b_gcn, hgb);
  k_mlp_mfma<<<NE / 128, 256, 0, stream>>>(ei, eattr, hgb, W1t, W_ee, b_ee, b1, W2, b2, out);
}

// Round 8
// 240.399 us; speedup vs baseline: 1.1651x; 1.1651x over previous
//
#include <hip/hip_runtime.h>

#define NN 50000
#define NE 800000
#define H  64
#define SCAN_B 196  // ceil(NN/256)

typedef __attribute__((ext_vector_type(8))) short bf16x8;
typedef __attribute__((ext_vector_type(4))) float f32x4;

__device__ __forceinline__ unsigned short f2bf(float f) {
  unsigned int u = __builtin_bit_cast(unsigned int, f);
  u += 0x7FFFu + ((u >> 16) & 1u);  // RNE
  return (unsigned short)(u >> 16);
}
__device__ __forceinline__ float bf2f(unsigned short u) {
  unsigned int v = ((unsigned int)u) << 16;
  return __builtin_bit_cast(float, v);
}

// ---------- prep: c-tables (block 0), W1 uv-frags (block 1), zero cnt (blocks 2+) ----
__global__ __launch_bounds__(256) void k_prep(
    const float* __restrict__ W1, const float* __restrict__ b1,
    const float* __restrict__ W_ee, const float* __restrict__ b_ee,
    float* __restrict__ thrS, float* __restrict__ cT,  // cT: float2[65][66]
    unsigned short* __restrict__ w1f, int* __restrict__ cnt) {
  const int t = threadIdx.x;
  if (blockIdx.x >= 2) {  // zero cnt
    int i = (blockIdx.x - 2) * 256 + t;
    if (i < NN) cnt[i] = 0;
    return;
  }
  if (blockIdx.x == 1) {  // W1 src/dst blocks -> 16 B-fragments for k_uv
    const int ln = t & 63, q = t >> 6;
    const int l15_ = ln & 15, l4_ = ln >> 4;
#pragma unroll
    for (int f = 0; f < 4; ++f) {
      const int idx = q * 4 + f;          // 0..15
      const int g = idx >> 3;             // 0 src, 1 dst
      const int ct = (idx >> 1) & 3;      // col tile
      const int c = idx & 1;              // k chunk
#pragma unroll
      for (int j = 0; j < 8; ++j) {
        const int k = g * 64 + c * 32 + l4_ * 8 + j;
        const int hcol = ct * 16 + l15_;
        w1f[(idx * 64 + ln) * 8 + j] = f2bf(W1[k * H + hcol]);
      }
    }
    return;
  }
  // block 0: interval tables for the edge-feature term (exact piecewise-linear)
  __shared__ float swee[64], sbee[64], sth[64];
  __shared__ int skx[64];
  if (t < 64) {
    const float w = W_ee[t], b = b_ee[t];
    swee[t] = w; sbee[t] = b;
    sth[t] = (w != 0.f) ? (-b / w) : __builtin_inff();
    skx[t] = t;
  }
  __syncthreads();
  for (int sz = 2; sz <= 64; sz <<= 1)
    for (int st = sz >> 1; st > 0; st >>= 1) {
      if (t < 64) {
        const int p = t ^ st;
        if (p > t) {
          const bool up = ((t & sz) == 0);
          const float a = sth[t], bb = sth[p];
          if (up ? (a > bb) : (a < bb)) {
            const int ka = skx[t];
            sth[t] = bb; sth[p] = a;
            skx[t] = skx[p]; skx[p] = ka;
          }
        }
      }
      __syncthreads();
    }
  if (t < 64) {
    const int h = t;
    float c1 = 0.f, c0 = b1[h];
    for (int k = 0; k < 64; ++k) {  // interval 0: ea = -inf
      const float w = swee[k], b = sbee[k];
      if (w < 0.f || (w == 0.f && b > 0.f)) {
        const float wv1 = W1[(128 + k) * H + h];
        c1 = fmaf(w, wv1, c1);
        c0 = fmaf(b, wv1, c0);
      }
    }
    float2* cT2 = (float2*)cT;
    cT2[h] = make_float2(c1, c0);
    for (int iv = 1; iv <= 64; ++iv) {
      const int ks = skx[iv - 1];
      const float w = swee[ks];
      const float s = (w > 0.f) ? 1.f : -1.f;  // activate vs deactivate crossing up
      const float wv1 = W1[(128 + ks) * H + h];
      c1 = fmaf(s * w, wv1, c1);
      c0 = fmaf(s * sbee[ks], wv1, c0);
      cT2[iv * 66 + h] = make_float2(c1, c0);
    }
    thrS[h] = sth[h];
  }
}

// ---------- count in-degree (dst) ----------
__global__ __launch_bounds__(256) void k_hist(const int* __restrict__ ei,
                                              int* __restrict__ cnt) {
  int e = blockIdx.x * 256 + threadIdx.x;
  atomicAdd(&cnt[ei[NE + e]], 1);
}

// ---------- hierarchical exclusive scan ----------
__global__ __launch_bounds__(256) void k_scan_local(const int* __restrict__ cnt,
                                                    int* __restrict__ loc,
                                                    int* __restrict__ bsum) {
  __shared__ int sh[256];
  const int t = threadIdx.x;
  const int i = blockIdx.x * 256 + t;
  const int v = (i < NN) ? cnt[i] : 0;
  sh[t] = v;
  __syncthreads();
  int val = v;
#pragma unroll
  for (int off = 1; off < 256; off <<= 1) {
    int o = (t >= off) ? sh[t - off] : 0;
    __syncthreads();
    val += o;
    sh[t] = val;
    __syncthreads();
  }
  if (i < NN) loc[i] = val - v;  // exclusive
  if (t == 255) bsum[blockIdx.x] = val;
}

__global__ __launch_bounds__(256) void k_scan_add(const int* __restrict__ loc,
                                                  const int* __restrict__ bsum,
                                                  int* __restrict__ rowptr,
                                                  int* __restrict__ cursor) {
  __shared__ int sh[256];
  const int t = threadIdx.x;
  sh[t] = (t < SCAN_B && t < (int)blockIdx.x) ? bsum[t] : 0;
  __syncthreads();
#pragma unroll
  for (int off = 128; off > 0; off >>= 1) {
    if (t < off) sh[t] += sh[t + off];
    __syncthreads();
  }
  const int boff = sh[0];
  const int i = blockIdx.x * 256 + t;
  if (i < NN) {
    const int r = loc[i] + boff;
    rowptr[i] = r;
    cursor[i] = r;
  }
  if (blockIdx.x == 0 && t == 0) rowptr[NN] = NE;
}

// ---------- node encoder + h0@W_gcn; htb = bf16(ht * dinv[n]) ----------
__global__ __launch_bounds__(256) void k_node(
    const float* __restrict__ x, const float* __restrict__ W_ne,
    const float* __restrict__ b_ne, const float* __restrict__ W_gcn,
    const int* __restrict__ cnt, unsigned short* __restrict__ htb) {
  __shared__ float sh[4][H];
  const int lane = threadIdx.x & 63;
  const int wv   = threadIdx.x >> 6;
  const int n    = blockIdx.x * 4 + wv;

  float acc = b_ne[lane];
#pragma unroll
  for (int k = 0; k < 5; ++k) acc = fmaf(x[n * 5 + k], W_ne[k * H + lane], acc);
  acc = fmaxf(acc, 0.0f);
  sh[wv][lane] = acc;
  __syncthreads();

  float hv = 0.0f;
#pragma unroll 8
  for (int k = 0; k < H; ++k) hv = fmaf(sh[wv][k], W_gcn[k * H + lane], hv);

  const float dv = rsqrtf((float)(cnt[n] + 1));
  htb[(size_t)n * H + lane] = f2bf(hv * dv);
}

// ---------- reorder: csr_src grouped by dst ----------
__global__ __launch_bounds__(256) void k_reorder(const int* __restrict__ ei,
                                                 int* __restrict__ cursor,
                                                 int* __restrict__ csr_src) {
  int e = blockIdx.x * 256 + threadIdx.x;
  int s = ei[e], d = ei[NE + e];
  int pos = atomicAdd(&cursor[d], 1);
  csr_src[pos] = s;
}

// ---------- gather: hgb[d] = bf16(dinv[d]*(htb[d] + sum htb[src]) + b_gcn) ----------
__global__ __launch_bounds__(256) void k_gather(
    const int* __restrict__ rowptr, const int* __restrict__ csr_src,
    const unsigned short* __restrict__ htb, const int* __restrict__ cnt,
    const float* __restrict__ b_gcn, unsigned short* __restrict__ hgb) {
  const int lane = threadIdx.x & 63;
  const int wv   = threadIdx.x >> 6;
  const int n    = blockIdx.x * 4 + wv;
  const int beg = rowptr[n], end = rowptr[n + 1];

  float sum = bf2f(htb[(size_t)n * H + lane]);  // self-loop term
  int i = beg;
#pragma unroll 1
  for (; i + 4 <= end; i += 4) {
    const int s0 = csr_src[i], s1 = csr_src[i + 1];
    const int s2 = csr_src[i + 2], s3 = csr_src[i + 3];
    const float v0 = bf2f(htb[(size_t)s0 * H + lane]);
    const float v1 = bf2f(htb[(size_t)s1 * H + lane]);
    const float v2 = bf2f(htb[(size_t)s2 * H + lane]);
    const float v3 = bf2f(htb[(size_t)s3 * H + lane]);
    sum += (v0 + v1) + (v2 + v3);
  }
#pragma unroll 1
  for (; i < end; ++i) sum += bf2f(htb[(size_t)csr_src[i] * H + lane]);

  const float dv = rsqrtf((float)(cnt[n] + 1));
  hgb[(size_t)n * H + lane] = f2bf(fmaf(dv, sum, b_gcn[lane]));
}

// ---------- u/v precompute: u = hg@W1s, v = hg@W1d (bf16), FULL 64 columns ----------
__global__ __launch_bounds__(256) void k_uv(const unsigned short* __restrict__ hgb,
                                            const unsigned short* __restrict__ w1f,
                                            unsigned short* __restrict__ u,
                                            unsigned short* __restrict__ v) {
  const int lane = threadIdx.x & 63;
  const int wv   = threadIdx.x >> 6;
  const int tile = blockIdx.x * 4 + wv;
  if (tile >= NN / 16) return;  // 3125 tiles
  const int n0 = tile * 16;
  const int l15 = lane & 15, l4 = lane >> 4;

  // A fragments: rows = nodes n0+l15, k = c*32 + l4*8 + j
  const unsigned short* ap = hgb + (size_t)(n0 + l15) * H + l4 * 8;
  const bf16x8 a0 = *(const bf16x8*)(ap);
  const bf16x8 a1 = *(const bf16x8*)(ap + 32);

  // B fragments: idx = g*8 + ct*2 + c
  bf16x8 bU[4][2], bV[4][2];
#pragma unroll
  for (int ct = 0; ct < 4; ++ct)
#pragma unroll
    for (int c = 0; c < 2; ++c) {
      bU[ct][c] = *(const bf16x8*)(w1f + ((0 + ct * 2 + c) * 64 + lane) * 8);
      bV[ct][c] = *(const bf16x8*)(w1f + ((8 + ct * 2 + c) * 64 + lane) * 8);
    }

  f32x4 au[4], av[4];
#pragma unroll
  for (int ct = 0; ct < 4; ++ct) {
    au[ct] = (f32x4)(0.f);
    av[ct] = (f32x4)(0.f);
    au[ct] = __builtin_amdgcn_mfma_f32_16x16x32_bf16(a0, bU[ct][0], au[ct], 0, 0, 0);
    au[ct] = __builtin_amdgcn_mfma_f32_16x16x32_bf16(a1, bU[ct][1], au[ct], 0, 0, 0);
    av[ct] = __builtin_amdgcn_mfma_f32_16x16x32_bf16(a0, bV[ct][0], av[ct], 0, 0, 0);
    av[ct] = __builtin_amdgcn_mfma_f32_16x16x32_bf16(a1, bV[ct][1], av[ct], 0, 0, 0);
  }

#pragma unroll
  for (int ct = 0; ct < 4; ++ct)
#pragma unroll
    for (int r = 0; r < 4; ++r) {  // D: row = l4*4+r (node), col = l15
      const size_t idx = (size_t)(n0 + l4 * 4 + r) * H + ct * 16 + l15;
      u[idx] = f2bf(au[ct][r]);
      v[idx] = f2bf(av[ct][r]);
    }
}

// ---------- edge kernel: out = W2^T relu(u[s]+v[d]+ea*c1[iv]+c0[iv]) + b2 ----------
#define ET 5  // tiles per wave; block covers 4*5*16 = 320 edges; grid = 2500
__global__ __launch_bounds__(256) void k_edge(
    const int* __restrict__ ei, const float* __restrict__ eattr,
    const unsigned short* __restrict__ u, const unsigned short* __restrict__ v,
    const float* __restrict__ thrS, const float* __restrict__ cT,
    const float* __restrict__ W2, const float* __restrict__ b2,
    float* __restrict__ out) {
  __shared__ float sThr[64];
  __shared__ float sCT[65 * 132];  // float2[65][66] interleaved (c1,c0)

  const int t = threadIdx.x;
  if (t < 64) sThr[t] = thrS[t];
  for (int i = t; i < 65 * 66; i += 256)
    ((float2*)sCT)[i] = ((const float2*)cT)[i];
  __syncthreads();

  const int lane = t & 63;
  const int wv   = t >> 6;
  const int l15  = lane & 15, l4 = lane >> 4;
  const float b2v = b2[0];

  float w2v[16];
#pragma unroll
  for (int j = 0; j < 16; ++j) w2v[j] = W2[l4 * 16 + j];

  const int tile0 = (blockIdx.x * 4 + wv) * ET;
#pragma unroll 1
  for (int tt = 0; tt < ET; ++tt) {
    const int eBase = (tile0 + tt) * 16;
    const int src = ei[eBase + l15];
    const int dst = ei[NE + eBase + l15];
    const float ea = eattr[eBase + l15];

    unsigned int ud[8], vd[8];
    {
      const unsigned short* up = u + (size_t)src * H + l4 * 16;
      const unsigned short* vp = v + (size_t)dst * H + l4 * 16;
      *(uint4*)(ud)     = *(const uint4*)(up);
      *(uint4*)(ud + 4) = *(const uint4*)(up + 8);
      *(uint4*)(vd)     = *(const uint4*)(vp);
      *(uint4*)(vd + 4) = *(const uint4*)(vp + 8);
    }

    int iv = 0;  // iv = #{sorted thr <= ea}
#pragma unroll
    for (int st = 64; st >= 1; st >>= 1) {
      const int nc = iv + st;
      if (nc <= 64 && sThr[nc - 1] <= ea) iv = nc;
    }

    const float* cp = sCT + iv * 132 + l4 * 32;
    float p = 0.0f;
#pragma unroll
    for (int r = 0; r < 8; ++r) {
      const float4 cc = *(const float4*)(cp + r * 4);  // (c1,c0) for h=2r, 2r+1
      const float ulo = __builtin_bit_cast(float, ud[r] << 16);
      const float uhi = __builtin_bit_cast(float, ud[r] & 0xFFFF0000u);
      const float vlo = __builtin_bit_cast(float, vd[r] << 16);
      const float vhi = __builtin_bit_cast(float, vd[r] & 0xFFFF0000u);
      const float z0 = ulo + vlo + fmaf(ea, cc.x, cc.y);
      const float z1 = uhi + vhi + fmaf(ea, cc.z, cc.w);
      p = fmaf(fmaxf(z0, 0.f), w2v[2 * r], p);
      p = fmaf(fmaxf(z1, 0.f), w2v[2 * r + 1], p);
    }

    p += __shfl_xor(p, 16);
    p += __shfl_xor(p, 32);
    if (lane < 16) out[eBase + lane] = p + b2v;
  }
}

extern "C" void kernel_launch(void* const* d_in, const int* in_sizes, int n_in,
                              void* d_out, int out_size, void* d_ws, size_t ws_size,
                              hipStream_t stream) {
  const float* x     = (const float*)d_in[0];
  const int*   ei    = (const int*)d_in[1];
  const float* eattr = (const float*)d_in[2];
  const float* W_ne  = (const float*)d_in[3];
  const float* b_ne  = (const float*)d_in[4];
  const float* W_ee  = (const float*)d_in[5];
  const float* b_ee  = (const float*)d_in[6];
  const float* W_gcn = (const float*)d_in[7];
  const float* b_gcn = (const float*)d_in[8];
  const float* W1    = (const float*)d_in[9];
  const float* b1    = (const float*)d_in[10];
  const float* W2    = (const float*)d_in[11];
  const float* b2    = (const float*)d_in[12];
  float* out = (float*)d_out;

  char* ws = (char*)d_ws;
  unsigned short* htb = (unsigned short*)(ws + 0);         // 6.4MB; u overlays after death
  unsigned short* hgb = (unsigned short*)(ws + 6400000);   // 6.4MB
  unsigned short* vT  = (unsigned short*)(ws + 12800000);  // 6.4MB
  int*   cnt     = (int*)(ws + 19200000);
  int*   rowptr  = (int*)(ws + 19400000);
  int*   cursor  = (int*)(ws + 19600016);
  int*   loc     = (int*)(ws + 19800016);
  int*   bsum    = (int*)(ws + 20000016);
  int*   csr_src = (int*)(ws + 20000816);                  // 3.2MB
  float* thrS    = (float*)(ws + 23200816);                // 256B
  float* cT      = (float*)(ws + 23201072);                // float2[65][66] = 34320B
  unsigned short* w1f = (unsigned short*)(ws + 23235392);  // 16 frags * 512B = 16384B
  unsigned short* uT  = htb;  // overlay: htb dead after k_gather

  k_prep<<<2 + SCAN_B, 256, 0, stream>>>(W1, b1, W_ee, b_ee, thrS, cT, w1f, cnt);
  k_hist<<<NE / 256, 256, 0, stream>>>(ei, cnt);
  k_scan_local<<<SCAN_B, 256, 0, stream>>>(cnt, loc, bsum);
  k_scan_add<<<SCAN_B, 256, 0, stream>>>(loc, bsum, rowptr, cursor);
  k_node<<<NN / 4, 256, 0, stream>>>(x, W_ne, b_ne, W_gcn, cnt, htb);
  k_reorder<<<NE / 256, 256, 0, stream>>>(ei, cursor, csr_src);
  k_gather<<<NN / 4, 256, 0, stream>>>(rowptr, csr_src, htb, cnt, b_gcn, hgb);
  k_uv<<<(NN / 16 + 3) / 4, 256, 0, stream>>>(hgb, w1f, uT, vT);
  k_edge<<<NE / (4 * ET * 16), 256, 0, stream>>>(ei, eattr, uT, vT, thrS, cT, W2, b2, out);
}

// Round 9
// 171.530 us; speedup vs baseline: 1.6329x; 1.4015x over previous
//
#include <hip/hip_runtime.h>

#define NN 50000
#define NE 800000
#define H  64
#define NBKT 196       // buckets of 256 dst values (196*256 = 50176 >= NN)
#define BCAP 8192      // per-bucket capacity (avg ~4082, +64 sigma margin)
#define BIN_CHUNK 2048 // edges per k_bin block

typedef __attribute__((ext_vector_type(8))) short bf16x8;
typedef __attribute__((ext_vector_type(4))) float f32x4;

__device__ __forceinline__ unsigned short f2bf(float f) {
  unsigned int u = __builtin_bit_cast(unsigned int, f);
  u += 0x7FFFu + ((u >> 16) & 1u);  // RNE
  return (unsigned short)(u >> 16);
}
__device__ __forceinline__ float bf2f(unsigned short u) {
  unsigned int v = ((unsigned int)u) << 16;
  return __builtin_bit_cast(float, v);
}

// ---------- prep: c-tables (block 0), W1 uv-frags (block 1), zero gcur (block 2) ----
__global__ __launch_bounds__(256) void k_prep(
    const float* __restrict__ W1, const float* __restrict__ b1,
    const float* __restrict__ W_ee, const float* __restrict__ b_ee,
    float* __restrict__ thrS, float* __restrict__ cT,  // cT: float2[65][66]
    unsigned short* __restrict__ w1f, int* __restrict__ gcur) {
  const int t = threadIdx.x;
  if (blockIdx.x == 2) {
    if (t < NBKT) gcur[t] = 0;
    return;
  }
  if (blockIdx.x == 1) {  // W1 src/dst blocks -> 16 B-fragments for k_uv
    const int ln = t & 63, q = t >> 6;
    const int l15_ = ln & 15, l4_ = ln >> 4;
#pragma unroll
    for (int f = 0; f < 4; ++f) {
      const int idx = q * 4 + f;          // 0..15
      const int g = idx >> 3;             // 0 src, 1 dst
      const int ct = (idx >> 1) & 3;      // col tile
      const int c = idx & 1;              // k chunk
#pragma unroll
      for (int j = 0; j < 8; ++j) {
        const int k = g * 64 + c * 32 + l4_ * 8 + j;
        const int hcol = ct * 16 + l15_;
        w1f[(idx * 64 + ln) * 8 + j] = f2bf(W1[k * H + hcol]);
      }
    }
    return;
  }
  // block 0: interval tables for the edge-feature term (exact piecewise-linear)
  __shared__ float swee[64], sbee[64], sth[64];
  __shared__ int skx[64];
  if (t < 64) {
    const float w = W_ee[t], b = b_ee[t];
    swee[t] = w; sbee[t] = b;
    sth[t] = (w != 0.f) ? (-b / w) : __builtin_inff();
    skx[t] = t;
  }
  __syncthreads();
  for (int sz = 2; sz <= 64; sz <<= 1)
    for (int st = sz >> 1; st > 0; st >>= 1) {
      if (t < 64) {
        const int p = t ^ st;
        if (p > t) {
          const bool up = ((t & sz) == 0);
          const float a = sth[t], bb = sth[p];
          if (up ? (a > bb) : (a < bb)) {
            const int ka = skx[t];
            sth[t] = bb; sth[p] = a;
            skx[t] = skx[p]; skx[p] = ka;
          }
        }
      }
      __syncthreads();
    }
  if (t < 64) {
    const int h = t;
    float c1 = 0.f, c0 = b1[h];
    for (int k = 0; k < 64; ++k) {  // interval 0: ea = -inf
      const float w = swee[k], b = sbee[k];
      if (w < 0.f || (w == 0.f && b > 0.f)) {
        const float wv1 = W1[(128 + k) * H + h];
        c1 = fmaf(w, wv1, c1);
        c0 = fmaf(b, wv1, c0);
      }
    }
    float2* cT2 = (float2*)cT;
    cT2[h] = make_float2(c1, c0);
    for (int iv = 1; iv <= 64; ++iv) {
      const int ks = skx[iv - 1];
      const float w = swee[ks];
      const float s = (w > 0.f) ? 1.f : -1.f;
      const float wv1 = W1[(128 + ks) * H + h];
      c1 = fmaf(s * w, wv1, c1);
      c0 = fmaf(s * sbee[ks], wv1, c0);
      cT2[iv * 66 + h] = make_float2(c1, c0);
    }
    thrS[h] = sth[h];
  }
}

// ---------- pass 1: bin edges by dst>>8 into bucket-strided gbin ----------
__global__ __launch_bounds__(256) void k_bin(const int* __restrict__ ei,
                                             unsigned int* __restrict__ gbin,
                                             int* __restrict__ gcur) {
  __shared__ int hist[NBKT], base[NBKT];
  const int t = threadIdx.x;
  if (t < NBKT) hist[t] = 0;
  __syncthreads();

  const int e0 = blockIdx.x * BIN_CHUNK;
  int srcv[8], dstv[8], loff[8];
#pragma unroll
  for (int j = 0; j < 8; ++j) {
    const int e = e0 + j * 256 + t;
    if (e < NE) {
      srcv[j] = ei[e];
      dstv[j] = ei[NE + e];
      loff[j] = atomicAdd(&hist[dstv[j] >> 8], 1);  // rank within (block,bucket)
    } else dstv[j] = -1;
  }
  __syncthreads();
  if (t < NBKT) base[t] = atomicAdd(&gcur[t], hist[t]);
  __syncthreads();
#pragma unroll
  for (int j = 0; j < 8; ++j) {
    if (dstv[j] >= 0) {
      const int b = dstv[j] >> 8;
      const int pos = base[b] + loff[j];
      if (pos < BCAP)  // statistically impossible overflow guard
        gbin[(size_t)b * BCAP + pos] =
            ((unsigned int)srcv[j] << 8) | (unsigned int)(dstv[j] & 255);
    }
  }
}

// ---------- pass 2: per-bucket exact CSR + rowrange + dinv ----------
__global__ __launch_bounds__(256) void k_pass2(const unsigned int* __restrict__ gbin,
                                               const int* __restrict__ gcur,
                                               unsigned short* __restrict__ gcsr,
                                               int2* __restrict__ rowrange,
                                               float* __restrict__ dinv) {
  __shared__ int hist[256], cur[256], sc[256];
  __shared__ unsigned short lcsr[BCAP];
  const int b = blockIdx.x, t = threadIdx.x;
  const int sz = min(gcur[b], BCAP);
  hist[t] = 0;
  __syncthreads();

  const unsigned int* bb = gbin + (size_t)b * BCAP;
  for (int i = t; i < sz; i += 256) atomicAdd(&hist[bb[i] & 255], 1);
  __syncthreads();

  int v = hist[t];
  const int cnt = v;
  sc[t] = v;
  __syncthreads();
#pragma unroll
  for (int off = 1; off < 256; off <<= 1) {
    const int o = (t >= off) ? sc[t - off] : 0;
    __syncthreads();
    v += o;
    sc[t] = v;
    __syncthreads();
  }
  const int ex = v - cnt;  // exclusive
  cur[t] = ex;
  const int d = b * 256 + t;
  if (d < NN) {
    const int beg = b * BCAP + ex;
    rowrange[d] = make_int2(beg, beg + cnt);
    dinv[d] = rsqrtf((float)(cnt + 1));
  }
  __syncthreads();

  for (int i = t; i < sz; i += 256) {
    const unsigned int en = bb[i];
    const int off = atomicAdd(&cur[en & 255], 1);
    lcsr[off] = (unsigned short)(en >> 8);
  }
  __syncthreads();
  for (int i = t; i < sz; i += 256) gcsr[(size_t)b * BCAP + i] = lcsr[i];
}

// ---------- node encoder + h0@W_gcn; htb = bf16(ht * dinv[n]) ----------
__global__ __launch_bounds__(256) void k_node(
    const float* __restrict__ x, const float* __restrict__ W_ne,
    const float* __restrict__ b_ne, const float* __restrict__ W_gcn,
    const float* __restrict__ dinv, unsigned short* __restrict__ htb) {
  __shared__ float sh[4][H];
  const int lane = threadIdx.x & 63;
  const int wv   = threadIdx.x >> 6;
  const int n    = blockIdx.x * 4 + wv;

  float acc = b_ne[lane];
#pragma unroll
  for (int k = 0; k < 5; ++k) acc = fmaf(x[n * 5 + k], W_ne[k * H + lane], acc);
  acc = fmaxf(acc, 0.0f);
  sh[wv][lane] = acc;
  __syncthreads();

  float hv = 0.0f;
#pragma unroll 8
  for (int k = 0; k < H; ++k) hv = fmaf(sh[wv][k], W_gcn[k * H + lane], hv);

  htb[(size_t)n * H + lane] = f2bf(hv * dinv[n]);
}

// ---------- gather: hgb[d] = bf16(dinv[d]*(htb[d] + sum htb[src]) + b_gcn) ----------
__global__ __launch_bounds__(256) void k_gather(
    const int2* __restrict__ rowrange, const unsigned short* __restrict__ gcsr,
    const unsigned short* __restrict__ htb, const float* __restrict__ dinv,
    const float* __restrict__ b_gcn, unsigned short* __restrict__ hgb) {
  const int lane = threadIdx.x & 63;
  const int wv   = threadIdx.x >> 6;
  const int n    = blockIdx.x * 4 + wv;
  const int2 rr = rowrange[n];

  float sum = bf2f(htb[(size_t)n * H + lane]);  // self-loop term
  int i = rr.x;
#pragma unroll 1
  for (; i + 4 <= rr.y; i += 4) {
    const int s0 = gcsr[i], s1 = gcsr[i + 1];
    const int s2 = gcsr[i + 2], s3 = gcsr[i + 3];
    const float v0 = bf2f(htb[(size_t)s0 * H + lane]);
    const float v1 = bf2f(htb[(size_t)s1 * H + lane]);
    const float v2 = bf2f(htb[(size_t)s2 * H + lane]);
    const float v3 = bf2f(htb[(size_t)s3 * H + lane]);
    sum += (v0 + v1) + (v2 + v3);
  }
#pragma unroll 1
  for (; i < rr.y; ++i) sum += bf2f(htb[(size_t)gcsr[i] * H + lane]);

  hgb[(size_t)n * H + lane] = f2bf(fmaf(dinv[n], sum, b_gcn[lane]));
}

// ---------- u/v precompute: u = hg@W1s, v = hg@W1d (bf16), full 64 columns ----------
__global__ __launch_bounds__(256) void k_uv(const unsigned short* __restrict__ hgb,
                                            const unsigned short* __restrict__ w1f,
                                            unsigned short* __restrict__ u,
                                            unsigned short* __restrict__ v) {
  const int lane = threadIdx.x & 63;
  const int wv   = threadIdx.x >> 6;
  const int tile = blockIdx.x * 4 + wv;
  if (tile >= NN / 16) return;
  const int n0 = tile * 16;
  const int l15 = lane & 15, l4 = lane >> 4;

  const unsigned short* ap = hgb + (size_t)(n0 + l15) * H + l4 * 8;
  const bf16x8 a0 = *(const bf16x8*)(ap);
  const bf16x8 a1 = *(const bf16x8*)(ap + 32);

  bf16x8 bU[4][2], bV[4][2];
#pragma unroll
  for (int ct = 0; ct < 4; ++ct)
#pragma unroll
    for (int c = 0; c < 2; ++c) {
      bU[ct][c] = *(const bf16x8*)(w1f + ((0 + ct * 2 + c) * 64 + lane) * 8);
      bV[ct][c] = *(const bf16x8*)(w1f + ((8 + ct * 2 + c) * 64 + lane) * 8);
    }

  f32x4 au[4], av[4];
#pragma unroll
  for (int ct = 0; ct < 4; ++ct) {
    au[ct] = (f32x4)(0.f);
    av[ct] = (f32x4)(0.f);
    au[ct] = __builtin_amdgcn_mfma_f32_16x16x32_bf16(a0, bU[ct][0], au[ct], 0, 0, 0);
    au[ct] = __builtin_amdgcn_mfma_f32_16x16x32_bf16(a1, bU[ct][1], au[ct], 0, 0, 0);
    av[ct] = __builtin_amdgcn_mfma_f32_16x16x32_bf16(a0, bV[ct][0], av[ct], 0, 0, 0);
    av[ct] = __builtin_amdgcn_mfma_f32_16x16x32_bf16(a1, bV[ct][1], av[ct], 0, 0, 0);
  }

#pragma unroll
  for (int ct = 0; ct < 4; ++ct)
#pragma unroll
    for (int r = 0; r < 4; ++r) {
      const size_t idx = (size_t)(n0 + l4 * 4 + r) * H + ct * 16 + l15;
      u[idx] = f2bf(au[ct][r]);
      v[idx] = f2bf(av[ct][r]);
    }
}

// ---------- edge kernel: out = W2^T relu(u[s]+v[d]+ea*c1[iv]+c0[iv]) + b2 ----------
#define ET 5  // tiles per wave; block covers 4*5*16 = 320 edges; grid = 2500
__global__ __launch_bounds__(256) void k_edge(
    const int* __restrict__ ei, const float* __restrict__ eattr,
    const unsigned short* __restrict__ u, const unsigned short* __restrict__ v,
    const float* __restrict__ thrS, const float* __restrict__ cT,
    const float* __restrict__ W2, const float* __restrict__ b2,
    float* __restrict__ out) {
  __shared__ float sThr[64];
  __shared__ float sCT[65 * 132];  // float2[65][66] interleaved (c1,c0)

  const int t = threadIdx.x;
  if (t < 64) sThr[t] = thrS[t];
  for (int i = t; i < 65 * 66; i += 256)
    ((float2*)sCT)[i] = ((const float2*)cT)[i];
  __syncthreads();

  const int lane = t & 63;
  const int wv   = t >> 6;
  const int l15  = lane & 15, l4 = lane >> 4;
  const float b2v = b2[0];

  float w2v[16];
#pragma unroll
  for (int j = 0; j < 16; ++j) w2v[j] = W2[l4 * 16 + j];

  const int tile0 = (blockIdx.x * 4 + wv) * ET;
#pragma unroll 1
  for (int tt = 0; tt < ET; ++tt) {
    const int eBase = (tile0 + tt) * 16;
    const int src = ei[eBase + l15];
    const int dst = ei[NE + eBase + l15];
    const float ea = eattr[eBase + l15];

    unsigned int ud[8], vd[8];
    {
      const unsigned short* up = u + (size_t)src * H + l4 * 16;
      const unsigned short* vp = v + (size_t)dst * H + l4 * 16;
      *(uint4*)(ud)     = *(const uint4*)(up);
      *(uint4*)(ud + 4) = *(const uint4*)(up + 8);
      *(uint4*)(vd)     = *(const uint4*)(vp);
      *(uint4*)(vd + 4) = *(const uint4*)(vp + 8);
    }

    int iv = 0;  // iv = #{sorted thr <= ea}
#pragma unroll
    for (int st = 64; st >= 1; st >>= 1) {
      const int nc = iv + st;
      if (nc <= 64 && sThr[nc - 1] <= ea) iv = nc;
    }

    const float* cp = sCT + iv * 132 + l4 * 32;
    float p = 0.0f;
#pragma unroll
    for (int r = 0; r < 8; ++r) {
      const float4 cc = *(const float4*)(cp + r * 4);
      const float ulo = __builtin_bit_cast(float, ud[r] << 16);
      const float uhi = __builtin_bit_cast(float, ud[r] & 0xFFFF0000u);
      const float vlo = __builtin_bit_cast(float, vd[r] << 16);
      const float vhi = __builtin_bit_cast(float, vd[r] & 0xFFFF0000u);
      const float z0 = ulo + vlo + fmaf(ea, cc.x, cc.y);
      const float z1 = uhi + vhi + fmaf(ea, cc.z, cc.w);
      p = fmaf(fmaxf(z0, 0.f), w2v[2 * r], p);
      p = fmaf(fmaxf(z1, 0.f), w2v[2 * r + 1], p);
    }

    p += __shfl_xor(p, 16);
    p += __shfl_xor(p, 32);
    if (lane < 16) out[eBase + lane] = p + b2v;
  }
}

extern "C" void kernel_launch(void* const* d_in, const int* in_sizes, int n_in,
                              void* d_out, int out_size, void* d_ws, size_t ws_size,
                              hipStream_t stream) {
  const float* x     = (const float*)d_in[0];
  const int*   ei    = (const int*)d_in[1];
  const float* eattr = (const float*)d_in[2];
  const float* W_ne  = (const float*)d_in[3];
  const float* b_ne  = (const float*)d_in[4];
  const float* W_ee  = (const float*)d_in[5];
  const float* b_ee  = (const float*)d_in[6];
  const float* W_gcn = (const float*)d_in[7];
  const float* b_gcn = (const float*)d_in[8];
  const float* W1    = (const float*)d_in[9];
  const float* b1    = (const float*)d_in[10];
  const float* W2    = (const float*)d_in[11];
  const float* b2    = (const float*)d_in[12];
  float* out = (float*)d_out;

  char* ws = (char*)d_ws;
  unsigned short* htb = (unsigned short*)(ws + 0);         // 6.4MB; u overlays after k_gather
  unsigned short* hgb = (unsigned short*)(ws + 6400000);   // 6.4MB
  unsigned int*   gbin = (unsigned int*)(ws + 12800000);   // 196*8192*4 = 6,422,528
  unsigned short* vT  = (unsigned short*)(ws + 12800000);  // overlays gbin (dead after pass2)
  unsigned short* gcsr = (unsigned short*)(ws + 19222528); // 196*8192*2 = 3,211,264
  int2*  rowrange = (int2*)(ws + 22433792);                // 400,000
  float* dinv    = (float*)(ws + 22833792);                // 200,000
  int*   gcur    = (int*)(ws + 23033792);                  // 800
  float* thrS    = (float*)(ws + 23034592);                // 256
  float* cT      = (float*)(ws + 23034848);                // 34,320
  unsigned short* w1f = (unsigned short*)(ws + 23069168);  // 16,384
  unsigned short* uT  = htb;

  k_prep<<<3, 256, 0, stream>>>(W1, b1, W_ee, b_ee, thrS, cT, w1f, gcur);
  k_bin<<<(NE + BIN_CHUNK - 1) / BIN_CHUNK, 256, 0, stream>>>(ei, gbin, gcur);
  k_pass2<<<NBKT, 256, 0, stream>>>(gbin, gcur, gcsr, rowrange, dinv);
  k_node<<<NN / 4, 256, 0, stream>>>(x, W_ne, b_ne, W_gcn, dinv, htb);
  k_gather<<<NN / 4, 256, 0, stream>>>(rowrange, gcsr, htb, dinv, b_gcn, hgb);
  k_uv<<<(NN / 16 + 3) / 4, 256, 0, stream>>>(hgb, w1f, uT, vT);
  k_edge<<<NE / (4 * ET * 16), 256, 0, stream>>>(ei, eattr, uT, vT, thrS, cT, W2, b2, out);
}

// Round 10
// 159.388 us; speedup vs baseline: 1.7573x; 1.0762x over previous
//
#include <hip/hip_runtime.h>

#define NN 50000
#define NE 800000
#define H  64
#define NBKT 196       // buckets of 256 dst values (196*256 = 50176 >= NN)
#define BCAP 8192      // per-bucket capacity (avg ~4082)
#define BIN_CHUNK 2048 // edges per k_bin block

typedef __attribute__((ext_vector_type(8))) short bf16x8;
typedef __attribute__((ext_vector_type(4))) float f32x4;

__device__ __forceinline__ unsigned short f2bf(float f) {
  unsigned int u = __builtin_bit_cast(unsigned int, f);
  u += 0x7FFFu + ((u >> 16) & 1u);  // RNE
  return (unsigned short)(u >> 16);
}
__device__ __forceinline__ float bf2f(unsigned short u) {
  unsigned int v = ((unsigned int)u) << 16;
  return __builtin_bit_cast(float, v);
}

// ---------- prep: c-tables (block 0), W1 uv-frags (block 1), zero gcur (block 2) ----
__global__ __launch_bounds__(256) void k_prep(
    const float* __restrict__ W1, const float* __restrict__ b1,
    const float* __restrict__ W_ee, const float* __restrict__ b_ee,
    float* __restrict__ thrS, float* __restrict__ cT,  // cT: float2[65][66]
    unsigned short* __restrict__ w1f, int* __restrict__ gcur) {
  const int t = threadIdx.x;
  if (blockIdx.x == 2) {
    if (t < NBKT) gcur[t] = 0;
    return;
  }
  if (blockIdx.x == 1) {  // W1 src/dst blocks -> 16 B-fragments for the uv GEMM
    const int ln = t & 63, q = t >> 6;
    const int l15_ = ln & 15, l4_ = ln >> 4;
#pragma unroll
    for (int f = 0; f < 4; ++f) {
      const int idx = q * 4 + f;          // 0..15
      const int g = idx >> 3;             // 0 src, 1 dst
      const int ct = (idx >> 1) & 3;      // col tile
      const int c = idx & 1;              // k chunk
#pragma unroll
      for (int j = 0; j < 8; ++j) {
        const int k = g * 64 + c * 32 + l4_ * 8 + j;
        const int hcol = ct * 16 + l15_;
        w1f[(idx * 64 + ln) * 8 + j] = f2bf(W1[k * H + hcol]);
      }
    }
    return;
  }
  // block 0: interval tables for the edge-feature term (exact piecewise-linear)
  __shared__ float swee[64], sbee[64], sth[64];
  __shared__ int skx[64];
  if (t < 64) {
    const float w = W_ee[t], b = b_ee[t];
    swee[t] = w; sbee[t] = b;
    sth[t] = (w != 0.f) ? (-b / w) : __builtin_inff();
    skx[t] = t;
  }
  __syncthreads();
  for (int sz = 2; sz <= 64; sz <<= 1)
    for (int st = sz >> 1; st > 0; st >>= 1) {
      if (t < 64) {
        const int p = t ^ st;
        if (p > t) {
          const bool up = ((t & sz) == 0);
          const float a = sth[t], bb = sth[p];
          if (up ? (a > bb) : (a < bb)) {
            const int ka = skx[t];
            sth[t] = bb; sth[p] = a;
            skx[t] = skx[p]; skx[p] = ka;
          }
        }
      }
      __syncthreads();
    }
  if (t < 64) {
    const int h = t;
    float c1 = 0.f, c0 = b1[h];
    for (int k = 0; k < 64; ++k) {  // interval 0: ea = -inf
      const float w = swee[k], b = sbee[k];
      if (w < 0.f || (w == 0.f && b > 0.f)) {
        const float wv1 = W1[(128 + k) * H + h];
        c1 = fmaf(w, wv1, c1);
        c0 = fmaf(b, wv1, c0);
      }
    }
    float2* cT2 = (float2*)cT;
    cT2[h] = make_float2(c1, c0);
    for (int iv = 1; iv <= 64; ++iv) {
      const int ks = skx[iv - 1];
      const float w = swee[ks];
      const float s = (w > 0.f) ? 1.f : -1.f;
      const float wv1 = W1[(128 + ks) * H + h];
      c1 = fmaf(s * w, wv1, c1);
      c0 = fmaf(s * sbee[ks], wv1, c0);
      cT2[iv * 66 + h] = make_float2(c1, c0);
    }
    thrS[h] = sth[h];
  }
}

// ---------- pass 1: bin edges by dst>>8 into bucket-strided gbin ----------
__global__ __launch_bounds__(256) void k_bin(const int* __restrict__ ei,
                                             unsigned int* __restrict__ gbin,
                                             int* __restrict__ gcur) {
  __shared__ int hist[NBKT], base[NBKT];
  const int t = threadIdx.x;
  if (t < NBKT) hist[t] = 0;
  __syncthreads();

  const int e0 = blockIdx.x * BIN_CHUNK;
  int srcv[8], dstv[8], loff[8];
#pragma unroll
  for (int j = 0; j < 8; ++j) {
    const int e = e0 + j * 256 + t;
    if (e < NE) {
      srcv[j] = ei[e];
      dstv[j] = ei[NE + e];
      loff[j] = atomicAdd(&hist[dstv[j] >> 8], 1);
    } else dstv[j] = -1;
  }
  __syncthreads();
  if (t < NBKT) base[t] = atomicAdd(&gcur[t], hist[t]);
  __syncthreads();
#pragma unroll
  for (int j = 0; j < 8; ++j) {
    if (dstv[j] >= 0) {
      const int b = dstv[j] >> 8;
      const int pos = base[b] + loff[j];
      if (pos < BCAP)
        gbin[(size_t)b * BCAP + pos] =
            ((unsigned int)srcv[j] << 8) | (unsigned int)(dstv[j] & 255);
    }
  }
}

// ---------- pass 2: per-bucket exact CSR + rowrange + dinv ----------
__global__ __launch_bounds__(256) void k_pass2(const unsigned int* __restrict__ gbin,
                                               const int* __restrict__ gcur,
                                               unsigned short* __restrict__ gcsr,
                                               int2* __restrict__ rowrange,
                                               float* __restrict__ dinv) {
  __shared__ int hist[256], cur[256], sc[256];
  __shared__ unsigned short lcsr[BCAP];
  const int b = blockIdx.x, t = threadIdx.x;
  const int sz = min(gcur[b], BCAP);
  hist[t] = 0;
  __syncthreads();

  const unsigned int* bb = gbin + (size_t)b * BCAP;
  for (int i = t; i < sz; i += 256) atomicAdd(&hist[bb[i] & 255], 1);
  __syncthreads();

  int v = hist[t];
  const int cnt = v;
  sc[t] = v;
  __syncthreads();
#pragma unroll
  for (int off = 1; off < 256; off <<= 1) {
    const int o = (t >= off) ? sc[t - off] : 0;
    __syncthreads();
    v += o;
    sc[t] = v;
    __syncthreads();
  }
  const int ex = v - cnt;  // exclusive
  cur[t] = ex;
  const int d = b * 256 + t;
  if (d < NN) {
    const int beg = b * BCAP + ex;
    rowrange[d] = make_int2(beg, beg + cnt);
    dinv[d] = rsqrtf((float)(cnt + 1));
  }
  __syncthreads();

  for (int i = t; i < sz; i += 256) {
    const unsigned int en = bb[i];
    const int off = atomicAdd(&cur[en & 255], 1);
    lcsr[off] = (unsigned short)(en >> 8);
  }
  __syncthreads();
  for (int i = t; i < sz; i += 256) gcsr[(size_t)b * BCAP + i] = lcsr[i];
}

// ---------- node encoder + h0@W_gcn; htb = bf16(ht * dinv[n]) ----------
__global__ __launch_bounds__(256) void k_node(
    const float* __restrict__ x, const float* __restrict__ W_ne,
    const float* __restrict__ b_ne, const float* __restrict__ W_gcn,
    const float* __restrict__ dinv, unsigned short* __restrict__ htb) {
  __shared__ float sh[4][H];
  const int lane = threadIdx.x & 63;
  const int wv   = threadIdx.x >> 6;
  const int n    = blockIdx.x * 4 + wv;

  float acc = b_ne[lane];
#pragma unroll
  for (int k = 0; k < 5; ++k) acc = fmaf(x[n * 5 + k], W_ne[k * H + lane], acc);
  acc = fmaxf(acc, 0.0f);
  sh[wv][lane] = acc;
  __syncthreads();

  float hv = 0.0f;
#pragma unroll 8
  for (int k = 0; k < H; ++k) hv = fmaf(sh[wv][k], W_gcn[k * H + lane], hv);

  htb[(size_t)n * H + lane] = f2bf(hv * dinv[n]);
}

// ---------- fused gather + uv: block = 16 nodes; LDS handoff (XOR-swizzled) ----------
__global__ __launch_bounds__(256) void k_gather_uv(
    const int2* __restrict__ rowrange, const unsigned short* __restrict__ gcsr,
    const unsigned short* __restrict__ htb, const float* __restrict__ dinv,
    const float* __restrict__ b_gcn, const unsigned short* __restrict__ w1f,
    unsigned short* __restrict__ u, unsigned short* __restrict__ v) {
  __shared__ unsigned short shg[16 * 64];  // 2KB, bf16 hg tile, XOR-swizzled rows
  const int lane = threadIdx.x & 63;
  const int wv   = threadIdx.x >> 6;
  const int n0   = blockIdx.x * 16;  // NN/16 = 3125 blocks exact
  const float bg = b_gcn[lane];

#pragma unroll 1
  for (int q = 0; q < 4; ++q) {
    const int nl = wv * 4 + q;
    const int n  = n0 + nl;
    const int2 rr = rowrange[n];
    float sum = bf2f(htb[(size_t)n * H + lane]);  // self-loop
    int i = rr.x;
#pragma unroll 1
    for (; i + 4 <= rr.y; i += 4) {
      const int s0 = gcsr[i], s1 = gcsr[i + 1];
      const int s2 = gcsr[i + 2], s3 = gcsr[i + 3];
      const float v0 = bf2f(htb[(size_t)s0 * H + lane]);
      const float v1 = bf2f(htb[(size_t)s1 * H + lane]);
      const float v2 = bf2f(htb[(size_t)s2 * H + lane]);
      const float v3 = bf2f(htb[(size_t)s3 * H + lane]);
      sum += (v0 + v1) + (v2 + v3);
    }
#pragma unroll 1
    for (; i < rr.y; ++i) sum += bf2f(htb[(size_t)gcsr[i] * H + lane]);

    const float hgv = fmaf(dinv[n], sum, bg);
    shg[((nl * 128 + lane * 2) ^ ((nl & 7) << 4)) >> 1] = f2bf(hgv);
  }
  __syncthreads();

  const int l15 = lane & 15, l4 = lane >> 4;
  // A fragments: row = node l15, k = c*32 + l4*8 + j (swizzled b128 reads)
  const bf16x8 a0 = *(const bf16x8*)(shg + (((l15 * 128 + l4 * 16) ^ ((l15 & 7) << 4)) >> 1));
  const bf16x8 a1 = *(const bf16x8*)(shg + (((l15 * 128 + 64 + l4 * 16) ^ ((l15 & 7) << 4)) >> 1));

  const int ct = wv;  // this wave's output column tile
  const bf16x8 bu0 = *(const bf16x8*)(w1f + ((ct * 2 + 0) * 64 + lane) * 8);
  const bf16x8 bu1 = *(const bf16x8*)(w1f + ((ct * 2 + 1) * 64 + lane) * 8);
  const bf16x8 bv0 = *(const bf16x8*)(w1f + ((8 + ct * 2 + 0) * 64 + lane) * 8);
  const bf16x8 bv1 = *(const bf16x8*)(w1f + ((8 + ct * 2 + 1) * 64 + lane) * 8);

  f32x4 au = (f32x4)(0.f), av = (f32x4)(0.f);
  au = __builtin_amdgcn_mfma_f32_16x16x32_bf16(a0, bu0, au, 0, 0, 0);
  au = __builtin_amdgcn_mfma_f32_16x16x32_bf16(a1, bu1, au, 0, 0, 0);
  av = __builtin_amdgcn_mfma_f32_16x16x32_bf16(a0, bv0, av, 0, 0, 0);
  av = __builtin_amdgcn_mfma_f32_16x16x32_bf16(a1, bv1, av, 0, 0, 0);

#pragma unroll
  for (int r = 0; r < 4; ++r) {  // D: row = l4*4+r (node), col = l15
    const size_t idx = (size_t)(n0 + l4 * 4 + r) * H + ct * 16 + l15;
    u[idx] = f2bf(au[r]);
    v[idx] = f2bf(av[r]);
  }
}

// ---------- edge kernel helpers ----------
__device__ __forceinline__ int find_iv(const float* __restrict__ sThr, float ea) {
  int iv = 0;
#pragma unroll
  for (int st = 64; st >= 1; st >>= 1) {
    const int nc = iv + st;
    if (nc <= 64 && sThr[nc - 1] <= ea) iv = nc;
  }
  return iv;
}

__device__ __forceinline__ void edge_compute(
    float ea, uint4 U0, uint4 U1, uint4 V0, uint4 V1,
    const float* __restrict__ sThr, const float* __restrict__ sCT,
    const float* __restrict__ w2v, int l4, int lane, float b2v,
    float* __restrict__ out, int obase) {
  const int iv = find_iv(sThr, ea);
  const float* cp = sCT + iv * 132 + l4 * 32;
  const unsigned int ud[8] = {U0.x, U0.y, U0.z, U0.w, U1.x, U1.y, U1.z, U1.w};
  const unsigned int vd[8] = {V0.x, V0.y, V0.z, V0.w, V1.x, V1.y, V1.z, V1.w};
  float p = 0.f;
#pragma unroll
  for (int r = 0; r < 8; ++r) {
    const float4 cc = *(const float4*)(cp + r * 4);
    const float ulo = __builtin_bit_cast(float, ud[r] << 16);
    const float uhi = __builtin_bit_cast(float, ud[r] & 0xFFFF0000u);
    const float vlo = __builtin_bit_cast(float, vd[r] << 16);
    const float vhi = __builtin_bit_cast(float, vd[r] & 0xFFFF0000u);
    const float z0 = ulo + vlo + fmaf(ea, cc.x, cc.y);
    const float z1 = uhi + vhi + fmaf(ea, cc.z, cc.w);
    p = fmaf(fmaxf(z0, 0.f), w2v[2 * r], p);
    p = fmaf(fmaxf(z1, 0.f), w2v[2 * r + 1], p);
  }
  p += __shfl_xor(p, 16);
  p += __shfl_xor(p, 32);
  if (lane < 16) out[obase + lane] = p + b2v;
}

// ---------- edge kernel: 2-deep pipelined; ET=5 tiles/wave ----------
#define ET 5  // block covers 4*5*16 = 320 edges; grid = 2500
__global__ __launch_bounds__(256) void k_edge(
    const int* __restrict__ ei, const float* __restrict__ eattr,
    const unsigned short* __restrict__ u, const unsigned short* __restrict__ v,
    const float* __restrict__ thrS, const float* __restrict__ cT,
    const float* __restrict__ W2, const float* __restrict__ b2,
    float* __restrict__ out) {
  __shared__ float sThr[64];
  __shared__ float sCT[65 * 132];  // float2[65][66] interleaved (c1,c0)

  const int t = threadIdx.x;
  if (t < 64) sThr[t] = thrS[t];
  for (int i = t; i < 65 * 66; i += 256)
    ((float2*)sCT)[i] = ((const float2*)cT)[i];
  __syncthreads();

  const int lane = t & 63;
  const int wv   = t >> 6;
  const int l15  = lane & 15, l4 = lane >> 4;
  const float b2v = b2[0];

  float w2v[16];
#pragma unroll
  for (int j = 0; j < 16; ++j) w2v[j] = W2[l4 * 16 + j];

  const int tile0 = (blockIdx.x * 4 + wv) * ET;
  int srcA[ET], dstA[ET];
  float eaA[ET];
#pragma unroll
  for (int tt = 0; tt < ET; ++tt) {
    srcA[tt] = ei[(tile0 + tt) * 16 + l15];
    dstA[tt] = ei[NE + (tile0 + tt) * 16 + l15];
    eaA[tt]  = eattr[(tile0 + tt) * 16 + l15];
  }

  uint4 Au0, Au1, Av0, Av1, Bu0, Bu1, Bv0, Bv1;

#define LOADUV(U0, U1, V0, V1, tt) {                              \
    const unsigned short* up = u + (size_t)srcA[tt] * H + l4 * 16; \
    const unsigned short* vp = v + (size_t)dstA[tt] * H + l4 * 16; \
    U0 = *(const uint4*)(up); U1 = *(const uint4*)(up + 8);        \
    V0 = *(const uint4*)(vp); V1 = *(const uint4*)(vp + 8); }

  LOADUV(Au0, Au1, Av0, Av1, 0);
  LOADUV(Bu0, Bu1, Bv0, Bv1, 1);
  edge_compute(eaA[0], Au0, Au1, Av0, Av1, sThr, sCT, w2v, l4, lane, b2v, out, (tile0 + 0) * 16);
  LOADUV(Au0, Au1, Av0, Av1, 2);
  edge_compute(eaA[1], Bu0, Bu1, Bv0, Bv1, sThr, sCT, w2v, l4, lane, b2v, out, (tile0 + 1) * 16);
  LOADUV(Bu0, Bu1, Bv0, Bv1, 3);
  edge_compute(eaA[2], Au0, Au1, Av0, Av1, sThr, sCT, w2v, l4, lane, b2v, out, (tile0 + 2) * 16);
  LOADUV(Au0, Au1, Av0, Av1, 4);
  edge_compute(eaA[3], Bu0, Bu1, Bv0, Bv1, sThr, sCT, w2v, l4, lane, b2v, out, (tile0 + 3) * 16);
  edge_compute(eaA[4], Au0, Au1, Av0, Av1, sThr, sCT, w2v, l4, lane, b2v, out, (tile0 + 4) * 16);
#undef LOADUV
}

extern "C" void kernel_launch(void* const* d_in, const int* in_sizes, int n_in,
                              void* d_out, int out_size, void* d_ws, size_t ws_size,
                              hipStream_t stream) {
  const float* x     = (const float*)d_in[0];
  const int*   ei    = (const int*)d_in[1];
  const float* eattr = (const float*)d_in[2];
  const float* W_ne  = (const float*)d_in[3];
  const float* b_ne  = (const float*)d_in[4];
  const float* W_ee  = (const float*)d_in[5];
  const float* b_ee  = (const float*)d_in[6];
  const float* W_gcn = (const float*)d_in[7];
  const float* b_gcn = (const float*)d_in[8];
  const float* W1    = (const float*)d_in[9];
  const float* b1    = (const float*)d_in[10];
  const float* W2    = (const float*)d_in[11];
  const float* b2    = (const float*)d_in[12];
  float* out = (float*)d_out;

  char* ws = (char*)d_ws;
  unsigned short* htb = (unsigned short*)(ws + 0);         // 6.4MB
  unsigned short* uT  = (unsigned short*)(ws + 6400000);   // 6.4MB (was hgb)
  unsigned int*   gbin = (unsigned int*)(ws + 12800000);   // 6,422,528
  unsigned short* vT  = (unsigned short*)(ws + 12800000);  // overlays gbin (dead after pass2)
  unsigned short* gcsr = (unsigned short*)(ws + 19222528); // 3,211,264
  int2*  rowrange = (int2*)(ws + 22433792);                // 400,000
  float* dinv    = (float*)(ws + 22833792);                // 200,000
  int*   gcur    = (int*)(ws + 23033792);                  // 800
  float* thrS    = (float*)(ws + 23034592);                // 256
  float* cT      = (float*)(ws + 23034848);                // 34,320
  unsigned short* w1f = (unsigned short*)(ws + 23069168);  // 16,384

  k_prep<<<3, 256, 0, stream>>>(W1, b1, W_ee, b_ee, thrS, cT, w1f, gcur);
  k_bin<<<(NE + BIN_CHUNK - 1) / BIN_CHUNK, 256, 0, stream>>>(ei, gbin, gcur);
  k_pass2<<<NBKT, 256, 0, stream>>>(gbin, gcur, gcsr, rowrange, dinv);
  k_node<<<NN / 4, 256, 0, stream>>>(x, W_ne, b_ne, W_gcn, dinv, htb);
  k_gather_uv<<<NN / 16, 256, 0, stream>>>(rowrange, gcsr, htb, dinv, b_gcn, w1f, uT, vT);
  k_edge<<<NE / (4 * ET * 16), 256, 0, stream>>>(ei, eattr, uT, vT, thrS, cT, W2, b2, out);
}